// Round 19
// baseline (73.766 us; speedup 1.0000x reference)
//
#include <hip/hip_runtime.h>
#include <stdint.h>

#define NTOK 16384

typedef __attribute__((ext_vector_type(8))) short short8;
typedef __attribute__((ext_vector_type(4))) float f32x4;
typedef __attribute__((ext_vector_type(16))) float f32x16;

// round-to-nearest-even f32 -> bf16 (bit pattern as short)
__device__ __forceinline__ short f2bf_rne(float f) {
  union { float f; unsigned u; } a; a.f = f;
  unsigned r = a.u + 0x7fffu + ((a.u >> 16) & 1u);
  return (short)(r >> 16);
}

// compiler-managed v_exp_f32 (raw asm bypasses the trans-op hazard recognizer)
__device__ __forceinline__ float fast_exp2(float x) {
#if __has_builtin(__builtin_amdgcn_exp2f)
  return __builtin_amdgcn_exp2f(x);
#else
  return exp2f(x);
#endif
}

// pack 4 f32 -> 4 OCP e4m3 bytes in one u32 (2x v_cvt_pk_fp8_f32)
__device__ __forceinline__ unsigned pack_fp8x4(float a, float b, float c, float d) {
  int r = __builtin_amdgcn_cvt_pk_fp8_f32(a, b, 0, false);   // bytes 1:0
  r = __builtin_amdgcn_cvt_pk_fp8_f32(c, d, r, true);        // bytes 3:2
  return (unsigned)r;
}

// sigma: involution on 0..31 swapping [4-7]<->[8-11] and [20-23]<->[24-27].
// Storing K row k at slot sigma(k) makes the 32x32 QK^T output's C-rows land
// so that exp'd P packs sequentially into the PV A-fragment (no cross-lane).
__device__ __forceinline__ int sigma32(int s) {
  int t = (s >> 2) & 3;
  return (t == 1 || t == 2) ? (s ^ 12) : s;
}

// ---------------- fused projections: V (frag-major fp8) + Q + K ---------
// Block = 32 tokens. V part: thread (c=tid&63, oct=tid>>6) computes 8
// tokens x 1 channel -> 8 e4m3 bytes, one contiguous 8B store into VF8
// (the exact 32x32x16 fp8 B-operand register image; per-frag 512B, lane*8).
// QK part: thread (qk=tid&15, tp=tid>>4) computes 2 tokens x 1 output dim;
// K scaled by 1/ln2 and stored sigma-permuted (bf16).
__global__ __launch_bounds__(256) void proj_all_kernel(
    const float* __restrict__ x,
    const float* __restrict__ Wq, const float* __restrict__ bq,
    const float* __restrict__ Wk, const float* __restrict__ bk,
    const float* __restrict__ Wv, const float* __restrict__ bv,
    short* __restrict__ Qp, short* __restrict__ Kp,
    unsigned char* __restrict__ VF8)
{
  __shared__ float sW[64 * 65];     // Wv, +1 pad
  __shared__ float sx[64][32];
  __shared__ float sb[64];
  __shared__ float sWqk[16 * 65];   // rows 0-7 Wq, 8-15 Wk, +1 pad
  __shared__ float sbqk[16];
  const int tid = threadIdx.x;
  const int n0 = blockIdx.x * 32;

  for (int i = tid; i < 4096; i += 256) sW[(i >> 6) * 65 + (i & 63)] = Wv[i];
  if (tid < 64) sb[tid] = bv[tid];
  for (int i = tid; i < 512; i += 256) {
    sWqk[(i >> 6) * 65 + (i & 63)]       = Wq[i];
    sWqk[((i >> 6) + 8) * 65 + (i & 63)] = Wk[i];
  }
  if (tid < 8)       sbqk[tid] = bq[tid];
  else if (tid < 16) sbqk[tid] = bk[tid - 8];
  for (int i = tid; i < 2048; i += 256) {
    const int r = i >> 5, col = i & 31;
    sx[r][col] = x[(size_t)r * NTOK + n0 + col];
  }
  __syncthreads();

  // ---- V (fp8 e4m3) ----
  {
    const int c   = tid & 63;
    const int oct = tid >> 6;
    float v[8];
    const float bias = sb[c];
#pragma unroll
    for (int j = 0; j < 8; ++j) v[j] = bias;
    for (int cp = 0; cp < 64; ++cp) {
      const float wv = sW[c * 65 + cp];
      const float* xr = &sx[cp][oct * 8];
#pragma unroll
      for (int j = 0; j < 8; ++j) v[j] += wv * xr[j];
    }
    const int n    = n0 + oct * 8;
    const int frag = (n >> 4) * 2 + (c >> 5);
    const int lane = ((n >> 3) & 1) * 32 + (c & 31);
    uint2 ov;
    ov.x = pack_fp8x4(v[0], v[1], v[2], v[3]);
    ov.y = pack_fp8x4(v[4], v[5], v[6], v[7]);
    *reinterpret_cast<uint2*>(VF8 + (size_t)frag * 512 + lane * 8) = ov;
  }

  // ---- Q, K (bf16) ----
  {
    const int qk = tid & 15;     // 0-7: Q dim, 8-15: K dim
    const int tp = tid >> 4;     // tokens tp and tp+16
    float a0 = 0.f, a1 = 0.f;
    for (int cp = 0; cp < 64; ++cp) {
      const float wv = sWqk[qk * 65 + cp];
      a0 += wv * sx[cp][tp];
      a1 += wv * sx[cp][tp + 16];
    }
    const float bias = sbqk[qk];
    if (qk < 8) {
      Qp[(size_t)(n0 + tp) * 8 + qk]      = f2bf_rne(a0 + bias);
      Qp[(size_t)(n0 + tp + 16) * 8 + qk] = f2bf_rne(a1 + bias);
    } else {
      const int d = qk - 8;
      Kp[(size_t)(n0 + sigma32(tp)) * 8 + d] =
          f2bf_rne((a0 + bias) * 1.44269504f);
      Kp[(size_t)(n0 + sigma32(tp + 16)) * 8 + d] =
          f2bf_rne((a1 + bias) * 1.44269504f);
    }
  }
}

// ---------------- fused attention: split-K in block, fp8 PV, ring-4 -----
// Block = 8 waves, all owning the SAME 32 q-rows; wave w covers key slice
// [w*2048, (w+1)*2048). NEW vs R18: prefetch ring deepened from 2 to 4
// half-tiles for BOTH K and V (R18 issued loads only ~1-2 steps (~134-270
// cyc) before use; L2 latency is ~200-400 cyc -> QK stalled at the head of
// the dependency chain every half-tile). Explicit unroll-4 keeps all buffer
// indices static. Clamps deleted: VF8 is padded +16KB in the workspace so
// unconditional past-end prefetches land in mapped, never-consumed scratch.
// lsum stays the exact f32 pairwise tree. Epilogue unchanged.
// NOTE: no s_setprio (R13: spill). Spill tripwire: WRITE_SIZE >> 4 MB.
__global__ __launch_bounds__(512, 4) void attn_fused_kernel(
    const short* __restrict__ Qp, const short* __restrict__ Kp,
    const unsigned char* __restrict__ VF8,
    const float* __restrict__ x, const float* __restrict__ gamma,
    float* __restrict__ out)
{
  __shared__ float lacc[8 * 2080];    // [w][q=32][65]  (pad kills conflicts)
  __shared__ float slsum[8 * 32];     // [w][q]

  const int tid  = threadIdx.x;
  const int w    = tid >> 6;          // key-slice 0..7
  const int lane = tid & 63;
  const int hi   = lane >> 5;
  const int ln   = lane & 31;
  const int q0   = blockIdx.x * 32;

  const short8 zero8 = {0,0,0,0,0,0,0,0};
  f32x16 zf16;
#pragma unroll
  for (int i = 0; i < 16; ++i) zf16[i] = 0.f;

  // Q fragment: B[k=8hi+e][q=ln]; hi half zero (d=8 padded to K=16)
  short8 qf = hi ? zero8
                 : *reinterpret_cast<const short8*>(Qp + (size_t)(q0 + ln) * 8);

  f32x16 acc0 = zf16, acc1 = zf16;   // c 0-31 / c 32-63
  float lsum = 0.f;

  const int kvlen = NTOK / 8;
  const int kv_lo = w * kvlen;
  const int nh    = kvlen / 32;      // 64 half-tiles of 32 keys

  const short* KP0 = Kp + ((size_t)kv_lo + ln) * 8;              // +h*256
  const unsigned char* VF0 = VF8 + (size_t)kv_lo * 64 + lane * 8; // +h*2048 B

  auto loadK = [&](int h, short8& kf) {
    kf = *reinterpret_cast<const short8*>(KP0 + (size_t)h * 256);
  };
  // 4 fp8 B-frags per half-tile (2 k-chunks x 2 c-chunks), 8B/lane each
  auto loadV = [&](int h, long (&vf)[4]) {
    const unsigned char* vp = VF0 + (size_t)h * 2048;
#pragma unroll
    for (int j = 0; j < 4; ++j)
      vf[j] = *reinterpret_cast<const long*>(vp + j * 512);
  };

  // exp + fp8-pack + pairwise f32 lsum tree for one half-tile's S
  auto expPack = [&](const f32x16& sv, long (&pa)[2]) {
    float e[16];
#pragma unroll
    for (int r = 0; r < 16; ++r) e[r] = fast_exp2(sv[r]);

    float t0 = (e[0] + e[1]) + (e[2] + e[3]);
    float t1 = (e[4] + e[5]) + (e[6] + e[7]);
    float t2 = (e[8] + e[9]) + (e[10] + e[11]);
    float t3 = (e[12] + e[13]) + (e[14] + e[15]);
    lsum += (t0 + t1) + (t2 + t3);

    unsigned u0 = pack_fp8x4(e[0],  e[1],  e[2],  e[3]);
    unsigned u1 = pack_fp8x4(e[4],  e[5],  e[6],  e[7]);
    unsigned u2 = pack_fp8x4(e[8],  e[9],  e[10], e[11]);
    unsigned u3 = pack_fp8x4(e[12], e[13], e[14], e[15]);
    pa[0] = (long)(((unsigned long long)u1 << 32) | u0);
    pa[1] = (long)(((unsigned long long)u3 << 32) | u2);
  };

  auto pvHalf = [&](const long (&pa)[2], const long (&vf)[4]) {
    acc0 = __builtin_amdgcn_mfma_f32_32x32x16_fp8_fp8(pa[0], vf[0], acc0, 0, 0, 0);
    acc1 = __builtin_amdgcn_mfma_f32_32x32x16_fp8_fp8(pa[0], vf[1], acc1, 0, 0, 0);
    acc0 = __builtin_amdgcn_mfma_f32_32x32x16_fp8_fp8(pa[1], vf[2], acc0, 0, 0, 0);
    acc1 = __builtin_amdgcn_mfma_f32_32x32x16_fp8_fp8(pa[1], vf[3], acc1, 0, 0, 0);
  };

  // prologue: ring filled with half-tiles 0..3; S(0) in flight
  short8 kf0, kf1, kf2, kf3;
  long vf0[4], vf1[4], vf2[4], vf3[4];
  loadK(0, kf0); loadV(0, vf0);
  loadK(1, kf1); loadV(1, vf1);
  loadK(2, kf2); loadV(2, vf2);
  loadK(3, kf3); loadV(3, vf3);
  f32x16 svA = __builtin_amdgcn_mfma_f32_32x32x16_bf16(kf0, qf, zf16, 0, 0, 0);
  f32x16 svB;

  // unroll-4 ring: at step h, consume S(h)+v(h); issue S(h+1); refill slot
  // h%4 with half-tile h+4 (4-step = ~540cyc load cover; past-end reads of
  // the final waves land in the VF8 pad, never consumed).
  for (int h = 0; h < nh; h += 4) {
    {
      long pa[2];
      svB = __builtin_amdgcn_mfma_f32_32x32x16_bf16(kf1, qf, zf16, 0, 0, 0);
      loadK(h + 4, kf0);
      expPack(svA, pa);
      pvHalf(pa, vf0);
      loadV(h + 4, vf0);
    }
    {
      long pa[2];
      svA = __builtin_amdgcn_mfma_f32_32x32x16_bf16(kf2, qf, zf16, 0, 0, 0);
      loadK(h + 5, kf1);
      expPack(svB, pa);
      pvHalf(pa, vf1);
      loadV(h + 5, vf1);
    }
    {
      long pa[2];
      svB = __builtin_amdgcn_mfma_f32_32x32x16_bf16(kf3, qf, zf16, 0, 0, 0);
      loadK(h + 6, kf2);
      expPack(svA, pa);
      pvHalf(pa, vf2);
      loadV(h + 6, vf2);
    }
    {
      long pa[2];
      svA = __builtin_amdgcn_mfma_f32_32x32x16_bf16(kf0, qf, zf16, 0, 0, 0);
      loadK(h + 7, kf3);
      expPack(svB, pa);
      pvHalf(pa, vf3);
      loadV(h + 7, vf3);
    }
  }

  // ---- epilogue: stage partials in LDS ----
  // C layout: qrow=(r&3)+8*(r>>2)+4*hi, col=ln (acc0) / 32+ln (acc1)
  float* la = &lacc[w * 2080];
#pragma unroll
  for (int r = 0; r < 16; ++r) {
    const int qrow = (r & 3) + 8 * (r >> 2) + 4 * hi;
    la[qrow * 65 + ln]      = acc0[r];
    la[qrow * 65 + 32 + ln] = acc1[r];
  }
  lsum += __shfl_xor(lsum, 32);      // combine hi halves (disjoint keys)
  if (lane < 32) slsum[w * 32 + ln] = lsum;
  __syncthreads();

  // ---- 8-way reduce + normalize + residual, c-major store ----
  const int q = tid & 31;
  float ls = 0.f;
#pragma unroll
  for (int w2 = 0; w2 < 8; ++w2) ls += slsum[w2 * 32 + q];
  const float inv = 1.f / ls;
  const float gam = gamma[0];

#pragma unroll
  for (int k = 0; k < 4; ++k) {
    const int c = (tid >> 5) + k * 16;
    float sum = 0.f;
#pragma unroll
    for (int w2 = 0; w2 < 8; ++w2) sum += lacc[w2 * 2080 + q * 65 + c];
    const size_t idx = (size_t)c * NTOK + q0 + q;
    out[idx] = gam * sum * inv + x[idx];
  }
}

extern "C" void kernel_launch(void* const* d_in, const int* in_sizes, int n_in,
                              void* d_out, int out_size, void* d_ws, size_t ws_size,
                              hipStream_t stream) {
  const float* x     = (const float*)d_in[0];
  const float* Wq    = (const float*)d_in[1];
  const float* bq    = (const float*)d_in[2];
  const float* Wk    = (const float*)d_in[3];
  const float* bk    = (const float*)d_in[4];
  const float* Wv    = (const float*)d_in[5];
  const float* bv    = (const float*)d_in[6];
  const float* gamma = (const float*)d_in[7];
  float* out = (float*)d_out;

  short* Qp = (short*)d_ws;                   // [N][8] bf16  (256 KB)
  short* Kp = Qp + (size_t)NTOK * 8;          // [N][8] bf16  (256 KB), sigma rows
  unsigned char* VF8 = (unsigned char*)(Kp + (size_t)NTOK * 8);  // fp8 V (1 MB)
  // VF8 is followed by >=16KB of unused workspace: ring-4 prefetch pad.

  proj_all_kernel<<<NTOK / 32, 256, 0, stream>>>(x, Wq, bq, Wk, bk, Wv, bv,
                                                 Qp, Kp, VF8);
  attn_fused_kernel<<<NTOK / 32, 512, 0, stream>>>(Qp, Kp, VF8, x, gamma, out);
}

// Round 20
// 66.674 us; speedup vs baseline: 1.1064x; 1.1064x over previous
//
#include <hip/hip_runtime.h>
#include <stdint.h>

#define NTOK 16384

typedef __attribute__((ext_vector_type(8))) short short8;
typedef __attribute__((ext_vector_type(4))) float f32x4;
typedef __attribute__((ext_vector_type(16))) float f32x16;

// round-to-nearest-even f32 -> bf16 (bit pattern as short)
__device__ __forceinline__ short f2bf_rne(float f) {
  union { float f; unsigned u; } a; a.f = f;
  unsigned r = a.u + 0x7fffu + ((a.u >> 16) & 1u);
  return (short)(r >> 16);
}

// compiler-managed v_exp_f32 (raw asm bypasses the trans-op hazard recognizer)
__device__ __forceinline__ float fast_exp2(float x) {
#if __has_builtin(__builtin_amdgcn_exp2f)
  return __builtin_amdgcn_exp2f(x);
#else
  return exp2f(x);
#endif
}

// pack 4 f32 -> 4 OCP e4m3 bytes in one u32 (2x v_cvt_pk_fp8_f32)
__device__ __forceinline__ unsigned pack_fp8x4(float a, float b, float c, float d) {
  int r = __builtin_amdgcn_cvt_pk_fp8_f32(a, b, 0, false);   // bytes 1:0
  r = __builtin_amdgcn_cvt_pk_fp8_f32(c, d, r, true);        // bytes 3:2
  return (unsigned)r;
}

// sigma: involution on 0..31 swapping [4-7]<->[8-11] and [20-23]<->[24-27].
// Storing K row k at slot sigma(k) makes the 32x32 QK^T output's C-rows land
// so that exp'd P packs sequentially into the PV A-fragment (no cross-lane).
__device__ __forceinline__ int sigma32(int s) {
  int t = (s >> 2) & 3;
  return (t == 1 || t == 2) ? (s ^ 12) : s;
}

// ---------------- fused projections: V (frag-major fp8) + Q + K ---------
// Block = 32 tokens. V part: thread (c=tid&63, oct=tid>>6) computes 8
// tokens x 1 channel -> 8 e4m3 bytes, one contiguous 8B store into VF8
// (the exact 32x32x16 fp8 B-operand register image; per-frag 512B, lane*8).
// QK part: thread (qk=tid&15, tp=tid>>4) computes 2 tokens x 1 output dim;
// K scaled by 1/ln2 and stored sigma-permuted (bf16).
__global__ __launch_bounds__(256) void proj_all_kernel(
    const float* __restrict__ x,
    const float* __restrict__ Wq, const float* __restrict__ bq,
    const float* __restrict__ Wk, const float* __restrict__ bk,
    const float* __restrict__ Wv, const float* __restrict__ bv,
    short* __restrict__ Qp, short* __restrict__ Kp,
    unsigned char* __restrict__ VF8)
{
  __shared__ float sW[64 * 65];     // Wv, +1 pad
  __shared__ float sx[64][32];
  __shared__ float sb[64];
  __shared__ float sWqk[16 * 65];   // rows 0-7 Wq, 8-15 Wk, +1 pad
  __shared__ float sbqk[16];
  const int tid = threadIdx.x;
  const int n0 = blockIdx.x * 32;

  for (int i = tid; i < 4096; i += 256) sW[(i >> 6) * 65 + (i & 63)] = Wv[i];
  if (tid < 64) sb[tid] = bv[tid];
  for (int i = tid; i < 512; i += 256) {
    sWqk[(i >> 6) * 65 + (i & 63)]       = Wq[i];
    sWqk[((i >> 6) + 8) * 65 + (i & 63)] = Wk[i];
  }
  if (tid < 8)       sbqk[tid] = bq[tid];
  else if (tid < 16) sbqk[tid] = bk[tid - 8];
  for (int i = tid; i < 2048; i += 256) {
    const int r = i >> 5, col = i & 31;
    sx[r][col] = x[(size_t)r * NTOK + n0 + col];
  }
  __syncthreads();

  // ---- V (fp8 e4m3) ----
  {
    const int c   = tid & 63;
    const int oct = tid >> 6;
    float v[8];
    const float bias = sb[c];
#pragma unroll
    for (int j = 0; j < 8; ++j) v[j] = bias;
    for (int cp = 0; cp < 64; ++cp) {
      const float wv = sW[c * 65 + cp];
      const float* xr = &sx[cp][oct * 8];
#pragma unroll
      for (int j = 0; j < 8; ++j) v[j] += wv * xr[j];
    }
    const int n    = n0 + oct * 8;
    const int frag = (n >> 4) * 2 + (c >> 5);
    const int lane = ((n >> 3) & 1) * 32 + (c & 31);
    uint2 ov;
    ov.x = pack_fp8x4(v[0], v[1], v[2], v[3]);
    ov.y = pack_fp8x4(v[4], v[5], v[6], v[7]);
    *reinterpret_cast<uint2*>(VF8 + (size_t)frag * 512 + lane * 8) = ov;
  }

  // ---- Q, K (bf16) ----
  {
    const int qk = tid & 15;     // 0-7: Q dim, 8-15: K dim
    const int tp = tid >> 4;     // tokens tp and tp+16
    float a0 = 0.f, a1 = 0.f;
    for (int cp = 0; cp < 64; ++cp) {
      const float wv = sWqk[qk * 65 + cp];
      a0 += wv * sx[cp][tp];
      a1 += wv * sx[cp][tp + 16];
    }
    const float bias = sbqk[qk];
    if (qk < 8) {
      Qp[(size_t)(n0 + tp) * 8 + qk]      = f2bf_rne(a0 + bias);
      Qp[(size_t)(n0 + tp + 16) * 8 + qk] = f2bf_rne(a1 + bias);
    } else {
      const int d = qk - 8;
      Kp[(size_t)(n0 + sigma32(tp)) * 8 + d] =
          f2bf_rne((a0 + bias) * 1.44269504f);
      Kp[(size_t)(n0 + sigma32(tp + 16)) * 8 + d] =
          f2bf_rne((a1 + bias) * 1.44269504f);
    }
  }
}

// ---------------- fused attention: fp8 PV, ring-4 loads, 1-deep S -------
// Block = 8 waves, all owning the SAME 32 q-rows; wave w covers key slice
// [w*2048, (w+1)*2048). vs R18/R19: prefetch ring stays 4-deep for K AND V,
// but the S (QK result) pipeline drops from 2-deep to 1-deep. R19 carried
// both (sv 32 + rings 48 regs) and spilled (WRITE 4->12MB, +11us). The
// QK->exp latency sv-2deep covered is ~40-60cyc (TLP-coverable); the
// load->use latency ring-4 covers is 200-400cyc (the expensive stall).
// Budget: acc 32 + sv 16 + Kring 16 + Vring 32 + qf/addr/temps ~24 = ~120.
// Past-end prefetches land in mapped workspace, never consumed.
// lsum stays the exact f32 pairwise tree. Epilogue unchanged.
// NOTE: no s_setprio (R13: spill). Spill tripwire: WRITE_SIZE >> 4 MB.
__global__ __launch_bounds__(512, 4) void attn_fused_kernel(
    const short* __restrict__ Qp, const short* __restrict__ Kp,
    const unsigned char* __restrict__ VF8,
    const float* __restrict__ x, const float* __restrict__ gamma,
    float* __restrict__ out)
{
  __shared__ float lacc[8 * 2080];    // [w][q=32][65]  (pad kills conflicts)
  __shared__ float slsum[8 * 32];     // [w][q]

  const int tid  = threadIdx.x;
  const int w    = tid >> 6;          // key-slice 0..7
  const int lane = tid & 63;
  const int hi   = lane >> 5;
  const int ln   = lane & 31;
  const int q0   = blockIdx.x * 32;

  const short8 zero8 = {0,0,0,0,0,0,0,0};
  f32x16 zf16;
#pragma unroll
  for (int i = 0; i < 16; ++i) zf16[i] = 0.f;

  // Q fragment: B[k=8hi+e][q=ln]; hi half zero (d=8 padded to K=16)
  short8 qf = hi ? zero8
                 : *reinterpret_cast<const short8*>(Qp + (size_t)(q0 + ln) * 8);

  f32x16 acc0 = zf16, acc1 = zf16;   // c 0-31 / c 32-63
  float lsum = 0.f;

  const int kvlen = NTOK / 8;
  const int kv_lo = w * kvlen;
  const int nh    = kvlen / 32;      // 64 half-tiles of 32 keys

  const short* KP0 = Kp + ((size_t)kv_lo + ln) * 8;              // +h*256
  const unsigned char* VF0 = VF8 + (size_t)kv_lo * 64 + lane * 8; // +h*2048 B

  auto loadK = [&](int h, short8& kf) {
    kf = *reinterpret_cast<const short8*>(KP0 + (size_t)h * 256);
  };
  // 4 fp8 B-frags per half-tile (2 k-chunks x 2 c-chunks), 8B/lane each
  auto loadV = [&](int h, long (&vf)[4]) {
    const unsigned char* vp = VF0 + (size_t)h * 2048;
#pragma unroll
    for (int j = 0; j < 4; ++j)
      vf[j] = *reinterpret_cast<const long*>(vp + j * 512);
  };

  // exp + fp8-pack + pairwise f32 lsum tree for one half-tile's S
  auto expPack = [&](const f32x16& sv, long (&pa)[2]) {
    float e[16];
#pragma unroll
    for (int r = 0; r < 16; ++r) e[r] = fast_exp2(sv[r]);

    float t0 = (e[0] + e[1]) + (e[2] + e[3]);
    float t1 = (e[4] + e[5]) + (e[6] + e[7]);
    float t2 = (e[8] + e[9]) + (e[10] + e[11]);
    float t3 = (e[12] + e[13]) + (e[14] + e[15]);
    lsum += (t0 + t1) + (t2 + t3);

    unsigned u0 = pack_fp8x4(e[0],  e[1],  e[2],  e[3]);
    unsigned u1 = pack_fp8x4(e[4],  e[5],  e[6],  e[7]);
    unsigned u2 = pack_fp8x4(e[8],  e[9],  e[10], e[11]);
    unsigned u3 = pack_fp8x4(e[12], e[13], e[14], e[15]);
    pa[0] = (long)(((unsigned long long)u1 << 32) | u0);
    pa[1] = (long)(((unsigned long long)u3 << 32) | u2);
  };

  auto pvHalf = [&](const long (&pa)[2], const long (&vf)[4]) {
    acc0 = __builtin_amdgcn_mfma_f32_32x32x16_fp8_fp8(pa[0], vf[0], acc0, 0, 0, 0);
    acc1 = __builtin_amdgcn_mfma_f32_32x32x16_fp8_fp8(pa[0], vf[1], acc1, 0, 0, 0);
    acc0 = __builtin_amdgcn_mfma_f32_32x32x16_fp8_fp8(pa[1], vf[2], acc0, 0, 0, 0);
    acc1 = __builtin_amdgcn_mfma_f32_32x32x16_fp8_fp8(pa[1], vf[3], acc1, 0, 0, 0);
  };

  // prologue: ring filled with half-tiles 0..3
  short8 kf0, kf1, kf2, kf3;
  long vf0[4], vf1[4], vf2[4], vf3[4];
  loadK(0, kf0); loadV(0, vf0);
  loadK(1, kf1); loadV(1, vf1);
  loadK(2, kf2); loadV(2, vf2);
  loadK(3, kf3); loadV(3, vf3);

  // unroll-4 ring, 1-deep S: each step consumes slot s and refills it with
  // half-tile h+4 (K load->use = 4 steps, V ~3.7 steps of own-stream
  // distance; past-end reads of the last 4 steps land in mapped workspace).
  for (int h = 0; h < nh; h += 4) {
    {
      f32x16 sv = __builtin_amdgcn_mfma_f32_32x32x16_bf16(kf0, qf, zf16, 0, 0, 0);
      loadK(h + 4, kf0);
      long pa[2];
      expPack(sv, pa);
      pvHalf(pa, vf0);
      loadV(h + 4, vf0);
    }
    {
      f32x16 sv = __builtin_amdgcn_mfma_f32_32x32x16_bf16(kf1, qf, zf16, 0, 0, 0);
      loadK(h + 5, kf1);
      long pa[2];
      expPack(sv, pa);
      pvHalf(pa, vf1);
      loadV(h + 5, vf1);
    }
    {
      f32x16 sv = __builtin_amdgcn_mfma_f32_32x32x16_bf16(kf2, qf, zf16, 0, 0, 0);
      loadK(h + 6, kf2);
      long pa[2];
      expPack(sv, pa);
      pvHalf(pa, vf2);
      loadV(h + 6, vf2);
    }
    {
      f32x16 sv = __builtin_amdgcn_mfma_f32_32x32x16_bf16(kf3, qf, zf16, 0, 0, 0);
      loadK(h + 7, kf3);
      long pa[2];
      expPack(sv, pa);
      pvHalf(pa, vf3);
      loadV(h + 7, vf3);
    }
  }

  // ---- epilogue: stage partials in LDS ----
  // C layout: qrow=(r&3)+8*(r>>2)+4*hi, col=ln (acc0) / 32+ln (acc1)
  float* la = &lacc[w * 2080];
#pragma unroll
  for (int r = 0; r < 16; ++r) {
    const int qrow = (r & 3) + 8 * (r >> 2) + 4 * hi;
    la[qrow * 65 + ln]      = acc0[r];
    la[qrow * 65 + 32 + ln] = acc1[r];
  }
  lsum += __shfl_xor(lsum, 32);      // combine hi halves (disjoint keys)
  if (lane < 32) slsum[w * 32 + ln] = lsum;
  __syncthreads();

  // ---- 8-way reduce + normalize + residual, c-major store ----
  const int q = tid & 31;
  float ls = 0.f;
#pragma unroll
  for (int w2 = 0; w2 < 8; ++w2) ls += slsum[w2 * 32 + q];
  const float inv = 1.f / ls;
  const float gam = gamma[0];

#pragma unroll
  for (int k = 0; k < 4; ++k) {
    const int c = (tid >> 5) + k * 16;
    float sum = 0.f;
#pragma unroll
    for (int w2 = 0; w2 < 8; ++w2) sum += lacc[w2 * 2080 + q * 65 + c];
    const size_t idx = (size_t)c * NTOK + q0 + q;
    out[idx] = gam * sum * inv + x[idx];
  }
}

extern "C" void kernel_launch(void* const* d_in, const int* in_sizes, int n_in,
                              void* d_out, int out_size, void* d_ws, size_t ws_size,
                              hipStream_t stream) {
  const float* x     = (const float*)d_in[0];
  const float* Wq    = (const float*)d_in[1];
  const float* bq    = (const float*)d_in[2];
  const float* Wk    = (const float*)d_in[3];
  const float* bk    = (const float*)d_in[4];
  const float* Wv    = (const float*)d_in[5];
  const float* bv    = (const float*)d_in[6];
  const float* gamma = (const float*)d_in[7];
  float* out = (float*)d_out;

  short* Qp = (short*)d_ws;                   // [N][8] bf16  (256 KB)
  short* Kp = Qp + (size_t)NTOK * 8;          // [N][8] bf16  (256 KB), sigma rows
  unsigned char* VF8 = (unsigned char*)(Kp + (size_t)NTOK * 8);  // fp8 V (1 MB)
  // VF8 is followed by megabytes of unused workspace: ring-4 prefetch pad.

  proj_all_kernel<<<NTOK / 32, 256, 0, stream>>>(x, Wq, bq, Wk, bk, Wv, bv,
                                                 Qp, Kp, VF8);
  attn_fused_kernel<<<NTOK / 32, 512, 0, stream>>>(Qp, Kp, VF8, x, gamma, out);
}